// Round 1
// baseline (383.813 us; speedup 1.0000x reference)
//
#include <hip/hip_runtime.h>
#include <math.h>

// Problem constants (B, N, D) = (256, 128, 128)
#define B_    256
#define N_    128
#define MAXP  30
#define OTHER_ 35      // D - 2*30 - 1 - 32
#define CIN1  131      // D + 64 - 2*30 - 1
#define NIDX  381      // 3*(N-1)

// ---------------------------------------------------------------------------
// indexes dtype detection: reference makes int64; harness note says int32.
// If int64 little-endian, the int32 view is (v,0,v,0,...) with v in [0,128).
// ---------------------------------------------------------------------------
__global__ void detect_idx_kernel(const int* __restrict__ raw, int* __restrict__ flag) {
  if (threadIdx.x == 0 && blockIdx.x == 0) {
    int is64 = 1;
    for (int i = 0; i < 64; ++i) {
      int lo = raw[2 * i];
      int hi = raw[2 * i + 1];
      if (hi != 0 || lo < 0 || lo >= N_) { is64 = 0; break; }
    }
    *flag = is64;
  }
}

__global__ void convert_idx_kernel(const void* __restrict__ raw, const int* __restrict__ flag,
                                   int* __restrict__ out, int cnt) {
  int i = blockIdx.x * blockDim.x + threadIdx.x;
  if (i >= cnt) return;
  if (*flag) out[i] = (int)((const long long*)raw)[i];
  else       out[i] = ((const int*)raw)[i];
}

// ---------------------------------------------------------------------------
// Weight transpose: w (O, CIN, 3) -> wT (Kpad, O), k = c*3+kk, zero-pad rows.
// ---------------------------------------------------------------------------
__global__ void transpose_w_kernel(const float* __restrict__ w, float* __restrict__ wT,
                                   int O, int Kreal, int Kpad) {
  int i = blockIdx.x * blockDim.x + threadIdx.x;
  if (i >= O * Kpad) return;
  int k = i / O;
  int o = i - k * O;
  wT[i] = (k < Kreal) ? w[o * Kreal + k] : 0.f;
}

// ---------------------------------------------------------------------------
// Embedding + collate: one wave per node.
// feature (B, 128, 128) [b][d][n]; collate (B, 128, 131) node-major.
// row c layout: [0..34] others, [35..98] emb-sum, [99..130] param.
// ---------------------------------------------------------------------------
__global__ __launch_bounds__(256) void embed_kernel(
    const float* __restrict__ feature,
    const float* __restrict__ col_embed,   // (200,32)
    const float* __restrict__ op_embed,    // (20,32)
    float* __restrict__ collate) {
  const int tid  = threadIdx.x;
  const int wave = tid >> 6;
  const int lane = tid & 63;
  const int b = blockIdx.x >> 5;
  const int n = ((blockIdx.x & 31) << 2) | wave;

  const float* fb = feature + ((size_t)b * 128) * 128 + n;  // stride 128 over d
  const int L = (int)fb[95 * 128];  // length in [0,30], uniform per wave

  float acc = 0.f;
  for (int i = 0; i < L; ++i) {
    int cv = (int)fb[(35 + i) * 128];
    int ov = (int)fb[(65 + i) * 128];
    acc += (lane < 32) ? col_embed[cv * 32 + lane] : op_embed[ov * 32 + (lane - 32)];
  }

  float* out = collate + ((size_t)b * 128 + n) * CIN1;
  out[35 + lane] = acc;                       // total (64)
  if (lane < 35) out[lane] = fb[lane * 128];  // others
  if (lane < 32) out[99 + lane] = fb[(96 + lane) * 128];  // param
}

// ---------------------------------------------------------------------------
// Tree conv layer: block = one batch element, 512 threads.
//   - stage X (128 x CIN) in LDS (optionally normalize+leaky on the way in)
//   - out[o][j] = bias[o] + sum_{c,kk} X[c][idx[3(j-1)+kk]] * w[o][c][kk], j>=1
//   - out[.][0] = 0
//   - block-reduce sum/sumsq of outputs -> statsOut[b] = {mean, 1/(std+1e-5)}
// Thread tile: 4 o x 4 j. wT is (3*CIN4, COUT) pre-transposed, zero-padded.
// ---------------------------------------------------------------------------
template <int CIN, int CINP, int COUT, bool NORM_IN>
__global__ __launch_bounds__(512, 1) void conv_kernel(
    const float* __restrict__ X,        // (B,128,CIN) node-major
    const int* __restrict__ idx,        // (B,381)
    const float* __restrict__ wT,       // (3*CIN4, COUT)
    const float* __restrict__ bias,     // (COUT)
    const float* __restrict__ statsIn,  // (B,2) or unused
    float* __restrict__ Y,              // (B,128,COUT) node-major
    float* __restrict__ statsOut) {     // (B,2)
  constexpr int CIN4 = (CIN + 3) & ~3;

  __shared__ float xs[128 * CINP];
  __shared__ int nb_s[NIDX];
  __shared__ double red[16];

  const int b = blockIdx.x;
  const int tid = threadIdx.x;

  float mean = 0.f, inv = 1.f;
  if (NORM_IN) { mean = statsIn[2 * b]; inv = statsIn[2 * b + 1]; }

  // ---- stage X into LDS (with pad channels zeroed) ----
  const float* __restrict__ Xb = X + (size_t)b * (128 * CIN);
  for (int t = tid; t < 128 * CIN4; t += 512) {
    int n = t / CIN4;
    int c = t - n * CIN4;
    float v = 0.f;
    if (c < CIN) {
      v = Xb[n * CIN + c];
      if (NORM_IN) {
        v = (v - mean) * inv;
        v = (v > 0.f) ? v : 0.01f * v;
      }
    }
    xs[n * CINP + c] = v;
  }
  if (tid < NIDX) nb_s[tid] = idx[b * NIDX + tid];
  __syncthreads();

  const int tx = tid & 15;   // o sub-tile (4 consecutive o)
  const int ty = tid >> 4;   // j group (4 consecutive j)

  int rowoff[4][3];
#pragma unroll
  for (int jj = 0; jj < 4; ++jj) {
    const int j = ty * 4 + jj;
#pragma unroll
    for (int kk = 0; kk < 3; ++kk) {
      int nbv = (j > 0) ? nb_s[(j - 1) * 3 + kk] : 0;
      rowoff[jj][kk] = nbv * CINP;
    }
  }

  double s_sum = 0.0, s_sq = 0.0;

  for (int oc = 0; oc < COUT; oc += 64) {
    float acc[4][4];
#pragma unroll
    for (int i = 0; i < 4; ++i)
#pragma unroll
      for (int jj = 0; jj < 4; ++jj) acc[i][jj] = 0.f;

    const float* wp = wT + oc + tx * 4;

    for (int c = 0; c < CIN4; c += 4) {
      float xq[4][3][4];
#pragma unroll
      for (int jj = 0; jj < 4; ++jj)
#pragma unroll
        for (int kk = 0; kk < 3; ++kk)
          *reinterpret_cast<float4*>(xq[jj][kk]) =
              *reinterpret_cast<const float4*>(&xs[rowoff[jj][kk] + c]);

#pragma unroll
      for (int cc = 0; cc < 4; ++cc) {
#pragma unroll
        for (int kk = 0; kk < 3; ++kk) {
          const float4 w4 = *reinterpret_cast<const float4*>(wp);
          wp += COUT;
#pragma unroll
          for (int jj = 0; jj < 4; ++jj) {
            const float xv = xq[jj][kk][cc];
            acc[0][jj] = fmaf(w4.x, xv, acc[0][jj]);
            acc[1][jj] = fmaf(w4.y, xv, acc[1][jj]);
            acc[2][jj] = fmaf(w4.z, xv, acc[2][jj]);
            acc[3][jj] = fmaf(w4.w, xv, acc[3][jj]);
          }
        }
      }
    }

    // ---- epilogue: bias, zero column, stats, store ----
    const float4 b4 = *reinterpret_cast<const float4*>(bias + oc + tx * 4);
#pragma unroll
    for (int jj = 0; jj < 4; ++jj) {
      const int j = ty * 4 + jj;
      float4 o4;
      if (j > 0) {
        o4.x = acc[0][jj] + b4.x;
        o4.y = acc[1][jj] + b4.y;
        o4.z = acc[2][jj] + b4.z;
        o4.w = acc[3][jj] + b4.w;
      } else {
        o4.x = 0.f; o4.y = 0.f; o4.z = 0.f; o4.w = 0.f;
      }
      s_sum += (double)o4.x + (double)o4.y + (double)o4.z + (double)o4.w;
      s_sq  += (double)o4.x * o4.x + (double)o4.y * o4.y +
               (double)o4.z * o4.z + (double)o4.w * o4.w;
      *reinterpret_cast<float4*>(Y + ((size_t)b * 128 + j) * COUT + oc + tx * 4) = o4;
    }
  }

  // ---- block reduction of stats (f64) ----
#pragma unroll
  for (int o = 32; o > 0; o >>= 1) {
    s_sum += __shfl_down(s_sum, o, 64);
    s_sq  += __shfl_down(s_sq, o, 64);
  }
  const int w = tid >> 6;
  if ((tid & 63) == 0) { red[w * 2] = s_sum; red[w * 2 + 1] = s_sq; }
  __syncthreads();
  if (tid == 0) {
    double S = 0.0, Q = 0.0;
    for (int i = 0; i < 8; ++i) { S += red[i * 2]; Q += red[i * 2 + 1]; }
    const double cnt = (double)COUT * 128.0;
    double m = S / cnt;
    double var = (Q - S * S / cnt) / (cnt - 1.0);
    if (var < 0.0) var = 0.0;
    double iv = 1.0 / (sqrt(var) + 1e-5);
    statsOut[2 * b] = (float)m;
    statsOut[2 * b + 1] = (float)iv;
  }
}

// ---------------------------------------------------------------------------
// Final: normalize conv3 out, maxpool over nodes, 2-layer MLP. Block=1 wave.
// ---------------------------------------------------------------------------
__global__ __launch_bounds__(64) void final_kernel(
    const float* __restrict__ Y3,      // (B,128,64)
    const float* __restrict__ stats,   // (B,2)
    const float* __restrict__ fw1,     // (32,64)
    const float* __restrict__ fb1,     // (32)
    const float* __restrict__ fw2,     // (1,32)
    const float* __restrict__ fb2,     // (1)
    float* __restrict__ out) {
  const int b = blockIdx.x;
  const int lane = threadIdx.x;
  const float mean = stats[2 * b];
  const float inv  = stats[2 * b + 1];
  const float* Yb = Y3 + (size_t)b * 128 * 64;

  float mx = -3.4e38f;
  for (int n = 0; n < 128; ++n) {
    float v = (Yb[n * 64 + lane] - mean) * inv;
    mx = fmaxf(mx, v);
  }
  __shared__ float pooled[64];
  __shared__ float hs[32];
  pooled[lane] = mx;
  __syncthreads();
  if (lane < 32) {
    float a = fb1[lane];
    for (int c = 0; c < 64; ++c) a = fmaf(pooled[c], fw1[lane * 64 + c], a);
    hs[lane] = fmaxf(a, 0.f);
  }
  __syncthreads();
  if (lane == 0) {
    float s = fb2[0];
    for (int t = 0; t < 32; ++t) s = fmaf(hs[t], fw2[t], s);
    out[b] = s;
  }
}

// ---------------------------------------------------------------------------
extern "C" void kernel_launch(void* const* d_in, const int* in_sizes, int n_in,
                              void* d_out, int out_size, void* d_ws, size_t ws_size,
                              hipStream_t stream) {
  const float* feature   = (const float*)d_in[0];
  const void*  indexes   = d_in[1];
  const float* col_embed = (const float*)d_in[2];
  const float* op_embed  = (const float*)d_in[3];
  const float* w1  = (const float*)d_in[4];
  const float* b1  = (const float*)d_in[5];
  const float* w2  = (const float*)d_in[6];
  const float* b2  = (const float*)d_in[7];
  const float* w3  = (const float*)d_in[8];
  const float* b3  = (const float*)d_in[9];
  const float* fw1 = (const float*)d_in[10];
  const float* fb1 = (const float*)d_in[11];
  const float* fw2 = (const float*)d_in[12];
  const float* fb2 = (const float*)d_in[13];
  float* out = (float*)d_out;

  // workspace carve (total ~78 MB)
  char* ws = (char*)d_ws;
  size_t off = 0;
  auto carve = [&](size_t bytes) -> char* {
    off = (off + 255) & ~(size_t)255;
    char* p = ws + off;
    off += bytes;
    return p;
  };
  int*   flag    = (int*)carve(sizeof(int));
  int*   idx32   = (int*)carve((size_t)B_ * NIDX * sizeof(int));
  float* wT1     = (float*)carve((size_t)396 * 256 * sizeof(float));   // 3*132 rows
  float* wT2     = (float*)carve((size_t)768 * 128 * sizeof(float));
  float* wT3     = (float*)carve((size_t)384 * 64 * sizeof(float));
  float* collate = (float*)carve((size_t)B_ * 128 * CIN1 * sizeof(float));
  float* Y1      = (float*)carve((size_t)B_ * 128 * 256 * sizeof(float));
  float* Y2      = (float*)carve((size_t)B_ * 128 * 128 * sizeof(float));
  float* Y3      = (float*)carve((size_t)B_ * 128 * 64 * sizeof(float));
  float* st1     = (float*)carve((size_t)B_ * 2 * sizeof(float));
  float* st2     = (float*)carve((size_t)B_ * 2 * sizeof(float));
  float* st3     = (float*)carve((size_t)B_ * 2 * sizeof(float));
  (void)ws_size; (void)in_sizes; (void)n_in; (void)out_size;

  const int idxcnt = B_ * NIDX;
  hipLaunchKernelGGL(detect_idx_kernel, dim3(1), dim3(64), 0, stream,
                     (const int*)indexes, flag);
  hipLaunchKernelGGL(convert_idx_kernel, dim3((idxcnt + 255) / 256), dim3(256), 0, stream,
                     indexes, flag, idx32, idxcnt);
  hipLaunchKernelGGL(transpose_w_kernel, dim3((256 * 396 + 255) / 256), dim3(256), 0, stream,
                     w1, wT1, 256, 393, 396);
  hipLaunchKernelGGL(transpose_w_kernel, dim3((128 * 768 + 255) / 256), dim3(256), 0, stream,
                     w2, wT2, 128, 768, 768);
  hipLaunchKernelGGL(transpose_w_kernel, dim3((64 * 384 + 255) / 256), dim3(256), 0, stream,
                     w3, wT3, 64, 384, 384);
  hipLaunchKernelGGL(embed_kernel, dim3(B_ * 32), dim3(256), 0, stream,
                     feature, col_embed, op_embed, collate);
  hipLaunchKernelGGL((conv_kernel<131, 136, 256, false>), dim3(B_), dim3(512), 0, stream,
                     collate, idx32, wT1, b1, (const float*)nullptr, Y1, st1);
  hipLaunchKernelGGL((conv_kernel<256, 260, 128, true>), dim3(B_), dim3(512), 0, stream,
                     Y1, idx32, wT2, b2, st1, Y2, st2);
  hipLaunchKernelGGL((conv_kernel<128, 132, 64, true>), dim3(B_), dim3(512), 0, stream,
                     Y2, idx32, wT3, b3, st2, Y3, st3);
  hipLaunchKernelGGL(final_kernel, dim3(B_), dim3(64), 0, stream,
                     Y3, st3, fw1, fb1, fw2, fb2, out);
}